// Round 6
// baseline (1356.918 us; speedup 1.0000x reference)
//
#include <hip/hip_runtime.h>
#include <math.h>

#define D 64
#define C 2048
#define ROWS (8 * 16384)   // B*N = 131072
#define BLOCK 256

// ---------------------------------------------------------------------------
// Kernel 1: per-code inverse L2 norm of the codebook -> ws (2048 floats, 8 KB)
// one wave (64 lanes) per code; lane k owns element k.
// ---------------------------------------------------------------------------
__global__ void vq_invnorm_kernel(const float* __restrict__ embed,
                                  float* __restrict__ invnorm) {
    int c = blockIdx.x;          // 0..C-1
    int k = threadIdx.x;         // 0..63
    float v = embed[c * D + k];
    float ss = v * v;
    // butterfly reduce across the 64-lane wave
    #pragma unroll
    for (int off = 32; off > 0; off >>= 1)
        ss += __shfl_xor(ss, off, 64);
    if (k == 0) {
        float n = sqrtf(ss);
        invnorm[c] = 1.0f / fmaxf(n, 1e-12f);
    }
}

// ---------------------------------------------------------------------------
// Kernel 2: fused dot / argmax / gather. One thread per row.
//   score(c) = (x_row . e_c) * invnorm[c]
// Positive per-row scale ||x_row|| is dropped: cannot change the argmax.
// Codebook accesses are wave-uniform -> scalar s_load; x row lives in VGPRs.
// ---------------------------------------------------------------------------
__global__ __launch_bounds__(BLOCK) void vq_argmax_kernel(
        const float* __restrict__ x,
        const float* __restrict__ embed,      // un-normalized, for gather
        const float* __restrict__ invnorm,    // 1/||e_c||
        float* __restrict__ out_q,            // [ROWS][D]
        float* __restrict__ out_i) {          // [ROWS] (indices as float)
    const int row = blockIdx.x * BLOCK + threadIdx.x;
    if (row >= ROWS) return;

    // ---- load this thread's x row into registers (16 x float4) ----
    float xr[D];
    const float4* xp = (const float4*)(x + (size_t)row * D);
    #pragma unroll
    for (int i = 0; i < D / 4; ++i) {
        float4 v = xp[i];
        xr[4 * i + 0] = v.x;
        xr[4 * i + 1] = v.y;
        xr[4 * i + 2] = v.z;
        xr[4 * i + 3] = v.w;
    }

    float best = -INFINITY;
    int   bidx = 0;

    // ---- sweep codebook, 2 codes per iteration, 4 partial sums each ----
    for (int c = 0; c < C; c += 2) {
        const float* e0 = embed + (size_t)c * D;         // uniform -> s_load
        const float* e1 = e0 + D;
        float a0 = 0.f, a1 = 0.f, a2 = 0.f, a3 = 0.f;
        float b0 = 0.f, b1 = 0.f, b2 = 0.f, b3 = 0.f;
        #pragma unroll
        for (int k = 0; k < D; k += 4) {
            a0 = fmaf(xr[k + 0], e0[k + 0], a0);
            a1 = fmaf(xr[k + 1], e0[k + 1], a1);
            a2 = fmaf(xr[k + 2], e0[k + 2], a2);
            a3 = fmaf(xr[k + 3], e0[k + 3], a3);
            b0 = fmaf(xr[k + 0], e1[k + 0], b0);
            b1 = fmaf(xr[k + 1], e1[k + 1], b1);
            b2 = fmaf(xr[k + 2], e1[k + 2], b2);
            b3 = fmaf(xr[k + 3], e1[k + 3], b3);
        }
        float s0 = ((a0 + a1) + (a2 + a3)) * invnorm[c];
        float s1 = ((b0 + b1) + (b2 + b3)) * invnorm[c + 1];
        // strict '>' keeps the FIRST max -> matches jnp.argmax tie rule
        if (s0 > best) { best = s0; bidx = c; }
        if (s1 > best) { best = s1; bidx = c + 1; }
    }

    // ---- gather the UN-normalized codebook row ----
    const float4* ep = (const float4*)(embed + (size_t)bidx * D);
    float4*       op = (float4*)(out_q + (size_t)row * D);
    #pragma unroll
    for (int i = 0; i < D / 4; ++i) op[i] = ep[i];

    out_i[row] = (float)bidx;
}

// ---------------------------------------------------------------------------
extern "C" void kernel_launch(void* const* d_in, const int* in_sizes, int n_in,
                              void* d_out, int out_size, void* d_ws, size_t ws_size,
                              hipStream_t stream) {
    const float* x     = (const float*)d_in[0];   // [8,16384,64] f32
    const float* embed = (const float*)d_in[1];   // [1,2048,64]  f32
    float* out_q = (float*)d_out;                 // quantize, 131072*64 floats
    float* out_i = out_q + (size_t)ROWS * D;      // indices as float, 131072
    float* invnorm = (float*)d_ws;                // 2048 floats scratch

    vq_invnorm_kernel<<<C, 64, 0, stream>>>(embed, invnorm);
    vq_argmax_kernel<<<ROWS / BLOCK, BLOCK, 0, stream>>>(x, embed, invnorm,
                                                         out_q, out_i);
}

// Round 7
// 910.705 us; speedup vs baseline: 1.4900x; 1.4900x over previous
//
#include <hip/hip_runtime.h>
#include <math.h>

#define D 64
#define C 2048
#define ROWS (8 * 16384)   // B*N = 131072
#define BLOCK 256

typedef float v4f __attribute__((ext_vector_type(4)));

// ---------------------------------------------------------------------------
// Kernel 1: per-code inverse L2 norm of the codebook -> ws (2048 floats)
// ---------------------------------------------------------------------------
__global__ void vq_invnorm_kernel(const float* __restrict__ embed,
                                  float* __restrict__ invnorm) {
    int c = blockIdx.x;          // 0..C-1
    int k = threadIdx.x;         // 0..63
    float v = embed[c * D + k];
    float ss = v * v;
    #pragma unroll
    for (int off = 32; off > 0; off >>= 1)
        ss += __shfl_xor(ss, off, 64);
    if (k == 0) invnorm[c] = 1.0f / fmaxf(sqrtf(ss), 1e-12f);
}

// ---------------------------------------------------------------------------
// Kernel 2: fused dot / argmax / gather. One thread per row.
// x row FORCED into 16 named float4 VGPRs (round-6 post-mortem: compiler
// re-loaded the x array from cache every iteration -> 34 TB L2 traffic,
// VGPR_Count=48, 1286 us). Epilogue is wave-cooperative for coalesced
// gather+store (round-6: 140 MB WRITE_SIZE from 256B-stride float4 scatter).
// ---------------------------------------------------------------------------
__global__ __launch_bounds__(BLOCK, 1) void vq_argmax_kernel(
        const float* __restrict__ x,
        const float* __restrict__ embed,      // un-normalized, for gather
        const float* __restrict__ invnorm,    // 1/||e_c||
        float* __restrict__ out_q,            // [ROWS][D]
        float* __restrict__ out_i) {          // [ROWS] (indices as float)
    const int row  = blockIdx.x * BLOCK + threadIdx.x;   // grid exact: < ROWS
    const int lane = threadIdx.x & 63;

    // ---- x row into 16 NAMED float4 registers, pinned ----
    const v4f* xp = (const v4f*)(x + (size_t)row * D);
    v4f x0 = xp[0],  x1 = xp[1],  x2 = xp[2],  x3 = xp[3];
    v4f x4 = xp[4],  x5 = xp[5],  x6 = xp[6],  x7 = xp[7];
    v4f x8 = xp[8],  x9 = xp[9],  x10 = xp[10], x11 = xp[11];
    v4f x12 = xp[12], x13 = xp[13], x14 = xp[14], x15 = xp[15];
    asm volatile("" : "+v"(x0), "+v"(x1), "+v"(x2), "+v"(x3));
    asm volatile("" : "+v"(x4), "+v"(x5), "+v"(x6), "+v"(x7));
    asm volatile("" : "+v"(x8), "+v"(x9), "+v"(x10), "+v"(x11));
    asm volatile("" : "+v"(x12), "+v"(x13), "+v"(x14), "+v"(x15));

    float best = -INFINITY;
    int   bidx = 0;

    const v4f* eb = (const v4f*)embed;        // 16 v4f per code

    for (int c = 0; c < C; c += 2) {
        const v4f* e0 = eb + c * 16;          // wave-uniform address
        float a0 = 0.f, a1 = 0.f, a2 = 0.f, a3 = 0.f;
        float b0 = 0.f, b1 = 0.f, b2 = 0.f, b3 = 0.f;
#define VQ_STEP(XI, I)                                              \
        {                                                           \
            v4f ev0 = e0[I];                                        \
            v4f ev1 = e0[16 + (I)];                                 \
            a0 = fmaf(XI.x, ev0.x, a0);                             \
            a1 = fmaf(XI.y, ev0.y, a1);                             \
            a2 = fmaf(XI.z, ev0.z, a2);                             \
            a3 = fmaf(XI.w, ev0.w, a3);                             \
            b0 = fmaf(XI.x, ev1.x, b0);                             \
            b1 = fmaf(XI.y, ev1.y, b1);                             \
            b2 = fmaf(XI.z, ev1.z, b2);                             \
            b3 = fmaf(XI.w, ev1.w, b3);                             \
        }
        VQ_STEP(x0, 0)   VQ_STEP(x1, 1)   VQ_STEP(x2, 2)   VQ_STEP(x3, 3)
        VQ_STEP(x4, 4)   VQ_STEP(x5, 5)   VQ_STEP(x6, 6)   VQ_STEP(x7, 7)
        VQ_STEP(x8, 8)   VQ_STEP(x9, 9)   VQ_STEP(x10, 10) VQ_STEP(x11, 11)
        VQ_STEP(x12, 12) VQ_STEP(x13, 13) VQ_STEP(x14, 14) VQ_STEP(x15, 15)
#undef VQ_STEP
        float s0 = ((a0 + a1) + (a2 + a3)) * invnorm[c];
        float s1 = ((b0 + b1) + (b2 + b3)) * invnorm[c + 1];
        // strict '>' keeps the FIRST max -> matches jnp.argmax tie rule
        if (s0 > best) { best = s0; bidx = c; }
        if (s1 > best) { best = s1; bidx = c + 1; }
    }

    // ---- wave-cooperative gather+store: rows of this wave are consecutive.
    // Iteration s: all 64 lanes write row (wrow0+s), element `lane`
    // -> one fully-coalesced 256B line per load and per store.
    const int wrow0 = row - lane;
    for (int s = 0; s < 64; ++s) {
        int bi = __shfl(bidx, s, 64);
        out_q[(size_t)(wrow0 + s) * D + lane] = embed[bi * D + lane];
    }
    out_i[row] = (float)bidx;
}

// ---------------------------------------------------------------------------
extern "C" void kernel_launch(void* const* d_in, const int* in_sizes, int n_in,
                              void* d_out, int out_size, void* d_ws, size_t ws_size,
                              hipStream_t stream) {
    const float* x     = (const float*)d_in[0];   // [8,16384,64] f32
    const float* embed = (const float*)d_in[1];   // [1,2048,64]  f32
    float* out_q = (float*)d_out;                 // quantize, 131072*64 floats
    float* out_i = out_q + (size_t)ROWS * D;      // indices as float, 131072
    float* invnorm = (float*)d_ws;                // 2048 floats scratch

    vq_invnorm_kernel<<<C, 64, 0, stream>>>(embed, invnorm);
    vq_argmax_kernel<<<ROWS / BLOCK, BLOCK, 0, stream>>>(x, embed, invnorm,
                                                         out_q, out_i);
}

// Round 9
// 307.232 us; speedup vs baseline: 4.4166x; 2.9642x over previous
//
#include <hip/hip_runtime.h>
#include <math.h>

#define D 64
#define C 2048
#define ROWS (8 * 16384)          // 131072
#define TAU 2e-3f                 // rescore margin (error bound ~8e-5, 25x headroom)

typedef short  bf16x8 __attribute__((ext_vector_type(8)));
typedef float  f32x4  __attribute__((ext_vector_type(4)));
typedef float  v4f    __attribute__((ext_vector_type(4)));

// ---- workspace layout (bytes); harness re-poisons ws each launch -> prep rebuilds all
#define WS_EHI 0                        // bf16 normalized codebook hi  [C*D*2 = 262144]
#define WS_ELO (WS_EHI + C * D * 2)     // bf16 normalized codebook lo  [262144]
#define WS_INV (WS_ELO + C * D * 2)     // f32 1/||e_c||                [8192]
#define WS_CNT (WS_INV + C * 4)         // int worklist count           [16]
#define WS_WL  (WS_CNT + 16)            // int worklist rows            [ROWS*4]

__device__ __forceinline__ unsigned short f2bf(float f) {   // RNE float->bf16
    unsigned u = __float_as_uint(f);
    return (unsigned short)((u + 0x7FFFu + ((u >> 16) & 1u)) >> 16);
}
__device__ __forceinline__ float bf2f(unsigned short h) {
    return __uint_as_float(((unsigned)h) << 16);
}

// ---------------------------------------------------------------------------
// prep: normalize codebook, split to bf16 hi/lo, store invnorm; zero worklist
// ---------------------------------------------------------------------------
__global__ void vq_prep(const float* __restrict__ embed, unsigned char* __restrict__ ws) {
    unsigned short* ehi = (unsigned short*)(ws + WS_EHI);
    unsigned short* elo = (unsigned short*)(ws + WS_ELO);
    float* invn = (float*)(ws + WS_INV);
    int c = blockIdx.x, k = threadIdx.x;
    if (c == 0 && k == 0) *(int*)(ws + WS_CNT) = 0;
    float v = embed[c * D + k];
    float ss = v * v;
    #pragma unroll
    for (int off = 32; off > 0; off >>= 1) ss += __shfl_xor(ss, off, 64);
    float inv = 1.0f / fmaxf(sqrtf(ss), 1e-12f);
    float e = v * inv;
    unsigned short h = f2bf(e);
    ehi[c * D + k] = h;
    elo[c * D + k] = f2bf(e - bf2f(h));
    if (k == 0) invn[c] = inv;
}

// ---------------------------------------------------------------------------
// pass 1: split-bf16 MFMA GEMM + fused argmax(+2nd max) + gather.
// 8 waves/block, wave = 32 rows (2x 16-row tiles), codebook staged 128 codes
// at a time in LDS (row stride 144 B -> bank stride 4 mod 32: 2-way max).
// ---------------------------------------------------------------------------
#define CHUNK   128
#define NCHUNK  (C / CHUNK)         // 16
#define LDS_ROW 144                 // 128 B data + 16 B pad
#define LDS_ARR (CHUNK * LDS_ROW)   // 18432

__global__ __launch_bounds__(512, 4) void vq_pass1(
        const float* __restrict__ x,
        const float* __restrict__ embed,        // un-normalized, for gather
        unsigned char* __restrict__ ws,
        float* __restrict__ out_q,
        float* __restrict__ out_i) {
    __shared__ unsigned char lds[2 * LDS_ARR];  // 36 KB
    int* cnt = (int*)(ws + WS_CNT);
    int* wl  = (int*)(ws + WS_WL);

    const int tid  = threadIdx.x;
    const int wid  = tid >> 6;
    const int lane = tid & 63;
    const int c15  = lane & 15;     // A row / B col / D col within tile
    const int g    = lane >> 4;     // k-group (A,B), row-group (D)
    const int wrow = blockIdx.x * 256 + wid * 32;

    // ---- A fragments: 32 x-rows -> bf16 hi/lo, resident for whole kernel ----
    bf16x8 Ahi[2][2], Alo[2][2];
    #pragma unroll
    for (int rt = 0; rt < 2; ++rt)
        #pragma unroll
        for (int kt = 0; kt < 2; ++kt) {
            const float* src = x + (size_t)(wrow + rt * 16 + c15) * D + kt * 32 + g * 8;
            v4f f0 = *(const v4f*)src;
            v4f f1 = *(const v4f*)(src + 4);
            float ff[8] = {f0.x, f0.y, f0.z, f0.w, f1.x, f1.y, f1.z, f1.w};
            bf16x8 h, l;
            #pragma unroll
            for (int i = 0; i < 8; ++i) {
                unsigned short hb = f2bf(ff[i]);
                h[i] = (short)hb;
                l[i] = (short)f2bf(ff[i] - bf2f(hb));
            }
            Ahi[rt][kt] = h; Alo[rt][kt] = l;
        }

    float m1[2][4], m2[2][4];
    int   i1[2][4];
    #pragma unroll
    for (int rt = 0; rt < 2; ++rt)
        #pragma unroll
        for (int j = 0; j < 4; ++j) { m1[rt][j] = -INFINITY; m2[rt][j] = -INFINITY; i1[rt][j] = 0; }

    for (int ch = 0; ch < NCHUNK; ++ch) {
        __syncthreads();
        // ---- stage 128 codes (hi+lo) into LDS: 2048 16B units / 512 threads ----
        const int cbase = ch * CHUNK;
        #pragma unroll
        for (int it = 0; it < 4; ++it) {
            int u    = it * 512 + tid;
            int arr  = u >> 10;                 // 0=hi, 1=lo
            int u2   = u & 1023;
            int code = u2 >> 3, k16 = u2 & 7;
            const unsigned short* srcb =
                (const unsigned short*)(ws + (arr ? WS_ELO : WS_EHI)) + (cbase + code) * D + k16 * 8;
            *(bf16x8*)(lds + arr * LDS_ARR + code * LDS_ROW + k16 * 16) = *(const bf16x8*)srcb;
        }
        __syncthreads();

        for (int ct = 0; ct < CHUNK / 16; ++ct) {
            const int boff = (ct * 16 + c15) * LDS_ROW + g * 16;
            bf16x8 Bhi0 = *(const bf16x8*)(lds + boff);
            bf16x8 Bhi1 = *(const bf16x8*)(lds + boff + 64);
            bf16x8 Blo0 = *(const bf16x8*)(lds + LDS_ARR + boff);
            bf16x8 Blo1 = *(const bf16x8*)(lds + LDS_ARR + boff + 64);
            const int ci = cbase + ct * 16 + c15;
            #pragma unroll
            for (int rt = 0; rt < 2; ++rt) {
                f32x4 acc = {0.f, 0.f, 0.f, 0.f};
                acc = __builtin_amdgcn_mfma_f32_16x16x32_bf16(Ahi[rt][0], Bhi0, acc, 0, 0, 0);
                acc = __builtin_amdgcn_mfma_f32_16x16x32_bf16(Ahi[rt][1], Bhi1, acc, 0, 0, 0);
                acc = __builtin_amdgcn_mfma_f32_16x16x32_bf16(Ahi[rt][0], Blo0, acc, 0, 0, 0);
                acc = __builtin_amdgcn_mfma_f32_16x16x32_bf16(Ahi[rt][1], Blo1, acc, 0, 0, 0);
                acc = __builtin_amdgcn_mfma_f32_16x16x32_bf16(Alo[rt][0], Bhi0, acc, 0, 0, 0);
                acc = __builtin_amdgcn_mfma_f32_16x16x32_bf16(Alo[rt][1], Bhi1, acc, 0, 0, 0);
                // fold 4 scores (rows g*4+j, code ci) into running top-2
                #pragma unroll
                for (int j = 0; j < 4; ++j) {
                    float s  = acc[j];
                    bool  gt = s > m1[rt][j];
                    m2[rt][j] = fmaxf(m2[rt][j], fminf(s, m1[rt][j]));
                    i1[rt][j] = gt ? ci : i1[rt][j];
                    m1[rt][j] = gt ? s  : m1[rt][j];
                }
            }
        }
    }

    // ---- 16-lane butterfly reduce (within c15), then cooperative gather ----
    #pragma unroll
    for (int rt = 0; rt < 2; ++rt)
        #pragma unroll
        for (int j = 0; j < 4; ++j) {
            float a1 = m1[rt][j], a2 = m2[rt][j];
            int   ai = i1[rt][j];
            #pragma unroll
            for (int off = 1; off < 16; off <<= 1) {
                float b1 = __shfl_xor(a1, off, 64);
                float b2 = __shfl_xor(a2, off, 64);
                int   bi = __shfl_xor(ai, off, 64);
                bool take = (b1 > a1) || (b1 == a1 && bi < ai);   // first-index tie rule
                a2 = fmaxf(fmaxf(a2, b2), fminf(a1, b1));
                a1 = take ? b1 : a1;
                ai = take ? bi : ai;
            }
            const int row = wrow + rt * 16 + g * 4 + j;
            // 16 lanes write 256 B coalesced: un-normalized codebook row
            v4f e = *(const v4f*)(embed + (size_t)ai * D + c15 * 4);
            *(v4f*)(out_q + (size_t)row * D + c15 * 4) = e;
            if (c15 == 0) {
                out_i[row] = (float)ai;
                if (a1 - a2 < TAU) {                 // ambiguous under split-bf16 error
                    int w = atomicAdd(cnt, 1);
                    if (w < ROWS) wl[w] = row;
                }
            }
        }
}

// ---------------------------------------------------------------------------
// pass 2: exact fp32 rescore of worklist rows (expected ~2% of rows).
// ---------------------------------------------------------------------------
__global__ __launch_bounds__(256) void vq_pass2(
        const float* __restrict__ x,
        const float* __restrict__ embed,
        unsigned char* __restrict__ ws,
        float* __restrict__ out_q,
        float* __restrict__ out_i) {
    __shared__ float xrow[D];
    __shared__ float sval[256];
    __shared__ int   sidx[256];
    const float* invn = (const float*)(ws + WS_INV);
    int n = *(const int*)(ws + WS_CNT);
    if (n > ROWS) n = ROWS;
    const int* wl = (const int*)(ws + WS_WL);

    for (int w = blockIdx.x; w < n; w += gridDim.x) {
        const int row = wl[w];
        __syncthreads();
        if (threadIdx.x < D) xrow[threadIdx.x] = x[(size_t)row * D + threadIdx.x];
        __syncthreads();
        float best = -INFINITY; int bi = 0;
        for (int c = threadIdx.x; c < C; c += 256) {      // increasing c: first-win via '>'
            float s = 0.f;
            #pragma unroll
            for (int k = 0; k < D; ++k) s = fmaf(xrow[k], embed[c * D + k], s);
            s *= invn[c];
            if (s > best) { best = s; bi = c; }
        }
        sval[threadIdx.x] = best; sidx[threadIdx.x] = bi;
        __syncthreads();
        for (int str = 128; str > 0; str >>= 1) {
            if (threadIdx.x < str) {
                float ov = sval[threadIdx.x + str]; int oi = sidx[threadIdx.x + str];
                if (ov > sval[threadIdx.x] ||
                    (ov == sval[threadIdx.x] && oi < sidx[threadIdx.x])) {
                    sval[threadIdx.x] = ov; sidx[threadIdx.x] = oi;
                }
            }
            __syncthreads();
        }
        const int bidx = sidx[0];
        if (threadIdx.x < D)
            out_q[(size_t)row * D + threadIdx.x] = embed[bidx * D + threadIdx.x];
        if (threadIdx.x == 0) out_i[row] = (float)bidx;
    }
}

// ---------------------------------------------------------------------------
extern "C" void kernel_launch(void* const* d_in, const int* in_sizes, int n_in,
                              void* d_out, int out_size, void* d_ws, size_t ws_size,
                              hipStream_t stream) {
    const float* x     = (const float*)d_in[0];   // [8,16384,64] f32
    const float* embed = (const float*)d_in[1];   // [1,2048,64]  f32
    float* out_q = (float*)d_out;                 // 131072*64 floats
    float* out_i = out_q + (size_t)ROWS * D;      // 131072 floats (indices)
    unsigned char* ws = (unsigned char*)d_ws;     // needs ~1.06 MB

    vq_prep <<<C, 64, 0, stream>>>(embed, ws);
    vq_pass1<<<ROWS / 256, 512, 0, stream>>>(x, embed, ws, out_q, out_i);
    vq_pass2<<<128, 256, 0, stream>>>(x, embed, ws, out_q, out_i);
}